// Round 3
// baseline (705.007 us; speedup 1.0000x reference)
//
#include <hip/hip_runtime.h>

#define B_ 2
#define L_ 2048
#define DM 1024
#define H_ 16
#define DK 64
#define ROWS (B_*L_)   // 4096

typedef __bf16 bf16x8 __attribute__((ext_vector_type(8)));
typedef float  f32x4  __attribute__((ext_vector_type(4)));
typedef unsigned short us8 __attribute__((ext_vector_type(8)));
typedef unsigned short us4 __attribute__((ext_vector_type(4)));

__device__ __forceinline__ bf16x8 ld8(const unsigned short* p) {
    return *reinterpret_cast<const bf16x8*>(p);
}

__device__ __forceinline__ unsigned short f2b(float f) {
    union { float f; unsigned u; } x; x.f = f;
    unsigned r = x.u + 0x7FFFu + ((x.u >> 16) & 1u);
    return (unsigned short)(r >> 16);
}

__device__ __forceinline__ float b2f(unsigned short h) {
    union { unsigned u; float f; } x; x.u = ((unsigned)h) << 16;
    return x.f;
}

// split f32 into hi+lo bf16 (x ~= hi + lo, error ~2^-18 |x|)
__device__ __forceinline__ void split2(float x, unsigned short& hi, unsigned short& lo) {
    hi = f2b(x);
    lo = f2b(x - b2f(hi));
}

// load 8 f32, split into hi/lo bf16x8 fragments
__device__ __forceinline__ void ldf8_split(const float* p, bf16x8& hi, bf16x8& lo) {
    const float4* q4 = (const float4*)p;
    float4 a = q4[0], b = q4[1];
    float vals[8] = {a.x, a.y, a.z, a.w, b.x, b.y, b.z, b.w};
    us8 h, l;
    #pragma unroll
    for (int i = 0; i < 8; i++) { unsigned short hh, ll; split2(vals[i], hh, ll); h[i] = hh; l[i] = ll; }
    hi = __builtin_bit_cast(bf16x8, h);
    lo = __builtin_bit_cast(bf16x8, l);
}

#define MFMA(a, b, c) __builtin_amdgcn_mfma_f32_16x16x32_bf16((a), (b), (c), 0, 0, 0)

// ---------------------------------------------------------------------------
// K0: transpose per-head weights (f32) [3][H][DM][DK] -> hi/lo bf16 [3][H][DK][DM]
// ---------------------------------------------------------------------------
__global__ __launch_bounds__(256) void k0_transpose_w(
    const float* __restrict__ wq,
    const float* __restrict__ wk,
    const float* __restrict__ wv,
    unsigned short* __restrict__ wt_hi,
    unsigned short* __restrict__ wt_lo)
{
    __shared__ unsigned tile[64][65];   // packed hi | lo<<16
    int bx = blockIdx.x;
    int which = bx / (H_ * 16);
    int rem   = bx % (H_ * 16);
    int h  = rem >> 4;
    int db = (rem & 15) * 64;
    const float* src = (which == 0) ? wq : (which == 1) ? wk : wv;

    int t = threadIdx.x;
    int r = t >> 2;             // d offset 0..63
    int c = (t & 3) * 16;       // dk offset {0,16,32,48}
    const float4* sp = (const float4*)(src + ((size_t)(h * DM + db + r)) * DK + c);
    #pragma unroll
    for (int i4 = 0; i4 < 4; i4++) {
        float4 f = sp[i4];
        float vals[4] = {f.x, f.y, f.z, f.w};
        #pragma unroll
        for (int j = 0; j < 4; j++) {
            unsigned short hi, lo; split2(vals[j], hi, lo);
            tile[r][c + i4 * 4 + j] = (unsigned)hi | ((unsigned)lo << 16);
        }
    }
    __syncthreads();

    int n   = t >> 2;           // dk index 0..63
    int d16 = (t & 3) * 16;
    __align__(16) unsigned short oh[16], ol[16];
    #pragma unroll
    for (int i = 0; i < 16; i++) {
        unsigned u = tile[d16 + i][n];
        oh[i] = (unsigned short)(u & 0xffffu);
        ol[i] = (unsigned short)(u >> 16);
    }
    size_t off = (((size_t)which * H_ + h) * DK + n) * DM + db + d16;
    *(us8*)(wt_hi + off)     = *(us8*)&oh[0];
    *(us8*)(wt_hi + off + 8) = *(us8*)&oh[8];
    *(us8*)(wt_lo + off)     = *(us8*)&ol[0];
    *(us8*)(wt_lo + off + 8) = *(us8*)&ol[8];
}

// ---------------------------------------------------------------------------
// K0b: split w_proj f32 [DM][DM] -> hi/lo bf16 planes (layout kept)
// ---------------------------------------------------------------------------
__global__ __launch_bounds__(256) void k0b_cvt_wp(
    const float* __restrict__ wp,
    unsigned short* __restrict__ wp_hi,
    unsigned short* __restrict__ wp_lo)
{
    int i = (blockIdx.x * 256 + threadIdx.x) * 4;
    float4 v = *(const float4*)(wp + i);
    float vals[4] = {v.x, v.y, v.z, v.w};
    us4 h, l;
    #pragma unroll
    for (int j = 0; j < 4; j++) { unsigned short hh, ll; split2(vals[j], hh, ll); h[j] = hh; l[j] = ll; }
    *(us4*)(wp_hi + i) = h;
    *(us4*)(wp_lo + i) = l;
}

// ---------------------------------------------------------------------------
// K1: fused q/k/v per-head projection GEMM, split-precision (3-term MFMA).
// Outputs hi/lo bf16 planes (f32-accurate).
// ---------------------------------------------------------------------------
__global__ __launch_bounds__(256) void k1_proj_qkv(
    const float* __restrict__ q,
    const float* __restrict__ k,
    const float* __restrict__ v,
    const unsigned short* __restrict__ wt_hi,  // [3][H][DK][DM]
    const unsigned short* __restrict__ wt_lo,
    unsigned short* __restrict__ qh_hi, unsigned short* __restrict__ qh_lo,
    unsigned short* __restrict__ kh_hi, unsigned short* __restrict__ kh_lo,
    unsigned short* __restrict__ vh_hi, unsigned short* __restrict__ vh_lo)
{
    int bx = blockIdx.x;
    int which = bx / (H_ * 32);
    int rem   = bx % (H_ * 32);
    int h     = rem >> 5;
    int mbase = (rem & 31) * 128;

    const float* X = (which == 0) ? q : (which == 1) ? k : v;
    size_t woff = ((size_t)which * H_ + h) * DK * DM;
    const unsigned short* Wh = wt_hi + woff;
    const unsigned short* Wl = wt_lo + woff;
    unsigned short* OH = ((which == 0) ? qh_hi : (which == 1) ? kh_hi : vh_hi) + (size_t)h * ROWS * DK;
    unsigned short* OL = ((which == 0) ? qh_lo : (which == 1) ? kh_lo : vh_lo) + (size_t)h * ROWS * DK;

    int wave = threadIdx.x >> 6, lane = threadIdx.x & 63;
    int quad = lane >> 4, l16 = lane & 15;
    int row0 = mbase + wave * 32;

    f32x4 acc[2][4];
    #pragma unroll
    for (int i = 0; i < 2; i++)
        #pragma unroll
        for (int j = 0; j < 4; j++) acc[i][j] = (f32x4)0.0f;

    for (int d = 0; d < DM; d += 32) {
        int koff = d + quad * 8;
        bf16x8 a0h, a0l, a1h, a1l;
        ldf8_split(X + (size_t)(row0 + l16) * DM + koff, a0h, a0l);
        ldf8_split(X + (size_t)(row0 + 16 + l16) * DM + koff, a1h, a1l);
        #pragma unroll
        for (int nt = 0; nt < 4; nt++) {
            size_t bo = (size_t)(nt * 16 + l16) * DM + koff;
            bf16x8 bh = ld8(Wh + bo);
            bf16x8 bl = ld8(Wl + bo);
            acc[0][nt] = MFMA(a0h, bh, acc[0][nt]);
            acc[0][nt] = MFMA(a0l, bh, acc[0][nt]);
            acc[0][nt] = MFMA(a0h, bl, acc[0][nt]);
            acc[1][nt] = MFMA(a1h, bh, acc[1][nt]);
            acc[1][nt] = MFMA(a1l, bh, acc[1][nt]);
            acc[1][nt] = MFMA(a1h, bl, acc[1][nt]);
        }
    }

    #pragma unroll
    for (int mt = 0; mt < 2; mt++)
        #pragma unroll
        for (int nt = 0; nt < 4; nt++)
            #pragma unroll
            for (int r = 0; r < 4; r++) {
                int row = row0 + mt * 16 + quad * 4 + r;
                unsigned short hh, ll;
                split2(acc[mt][nt][r], hh, ll);
                OH[(size_t)row * DK + nt * 16 + l16] = hh;
                OL[(size_t)row * DK + nt * 16 + l16] = ll;
            }
}

// ---------------------------------------------------------------------------
// K2: flash attention per (h, b, 64-row Q tile), split-precision throughout.
// ---------------------------------------------------------------------------
__global__ __launch_bounds__(256) void k2_attn(
    const unsigned short* __restrict__ qh_hi, const unsigned short* __restrict__ qh_lo,
    const unsigned short* __restrict__ kh_hi, const unsigned short* __restrict__ kh_lo,
    const unsigned short* __restrict__ vh_hi, const unsigned short* __restrict__ vh_lo,
    unsigned short* __restrict__ x2_hi, unsigned short* __restrict__ x2_lo)
{
    __shared__ __align__(16) unsigned short vth[DK][72], vtl[DK][72];      // V^T hi/lo
    __shared__ __align__(16) unsigned short pldh[4][16][72], pldl[4][16][72];

    int bx = blockIdx.x;
    int h  = bx >> 6;
    int b  = (bx >> 5) & 1;
    int qt = bx & 31;
    int qbase = qt * 64;

    size_t hoff = ((size_t)h * ROWS + b * L_) * DK;
    const unsigned short* qph = qh_hi + hoff;
    const unsigned short* qpl = qh_lo + hoff;
    const unsigned short* kph = kh_hi + hoff;
    const unsigned short* kpl = kh_lo + hoff;
    const unsigned short* vph = vh_hi + hoff;
    const unsigned short* vpl = vh_lo + hoff;

    int wave = threadIdx.x >> 6, lane = threadIdx.x & 63;
    int quad = lane >> 4, l16 = lane & 15;

    int qrow = qbase + wave * 16 + l16;
    bf16x8 qa0h = ld8(qph + (size_t)qrow * DK + quad * 8);
    bf16x8 qa1h = ld8(qph + (size_t)qrow * DK + 32 + quad * 8);
    bf16x8 qa0l = ld8(qpl + (size_t)qrow * DK + quad * 8);
    bf16x8 qa1l = ld8(qpl + (size_t)qrow * DK + 32 + quad * 8);

    float m_i[4], l_i[4];
    f32x4 o[4];
    #pragma unroll
    for (int r = 0; r < 4; r++) { m_i[r] = -1e30f; l_i[r] = 0.0f; }
    #pragma unroll
    for (int nt = 0; nt < 4; nt++) o[nt] = (f32x4)0.0f;

    for (int kt = 0; kt < 32; kt++) {
        int kb = kt * 64;
        {   // stage V^T hi/lo into LDS
            int t = threadIdx.x;
            int key = t >> 2, c = (t & 3) * 16;
            size_t so = (size_t)(kb + key) * DK + c;
            us8 h0 = *(const us8*)(vph + so);
            us8 h1 = *(const us8*)(vph + so + 8);
            us8 l0 = *(const us8*)(vpl + so);
            us8 l1 = *(const us8*)(vpl + so + 8);
            #pragma unroll
            for (int i = 0; i < 8; i++) { vth[c + i][key] = h0[i]; vth[c + 8 + i][key] = h1[i]; }
            #pragma unroll
            for (int i = 0; i < 8; i++) { vtl[c + i][key] = l0[i]; vtl[c + 8 + i][key] = l1[i]; }
        }
        __syncthreads();

        // S = Q K^T (split: hi*hi + lo*hi + hi*lo)
        f32x4 s[4];
        #pragma unroll
        for (int nt = 0; nt < 4; nt++) s[nt] = (f32x4)0.0f;
        #pragma unroll
        for (int nt = 0; nt < 4; nt++) {
            size_t ko = (size_t)(kb + nt * 16 + l16) * DK;
            bf16x8 b0h = ld8(kph + ko + quad * 8);
            bf16x8 b1h = ld8(kph + ko + 32 + quad * 8);
            bf16x8 b0l = ld8(kpl + ko + quad * 8);
            bf16x8 b1l = ld8(kpl + ko + 32 + quad * 8);
            s[nt] = MFMA(qa0h, b0h, s[nt]);
            s[nt] = MFMA(qa0l, b0h, s[nt]);
            s[nt] = MFMA(qa0h, b0l, s[nt]);
            s[nt] = MFMA(qa1h, b1h, s[nt]);
            s[nt] = MFMA(qa1l, b1h, s[nt]);
            s[nt] = MFMA(qa1h, b1l, s[nt]);
        }

        // online softmax (rows owned by this quad: quad*4 + r)
        #pragma unroll
        for (int r = 0; r < 4; r++) {
            float mx = fmaxf(fmaxf(s[0][r], s[1][r]), fmaxf(s[2][r], s[3][r]));
            #pragma unroll
            for (int off = 1; off < 16; off <<= 1)
                mx = fmaxf(mx, __shfl_xor(mx, off, 16));
            float mnew  = fmaxf(m_i[r], mx);
            float alpha = __expf(m_i[r] - mnew);
            float rs = 0.0f;
            #pragma unroll
            for (int nt = 0; nt < 4; nt++) {
                float p = __expf(s[nt][r] - mnew);
                s[nt][r] = p;
                rs += p;
            }
            #pragma unroll
            for (int off = 1; off < 16; off <<= 1)
                rs += __shfl_xor(rs, off, 16);
            l_i[r] = l_i[r] * alpha + rs;
            m_i[r] = mnew;
            #pragma unroll
            for (int nt = 0; nt < 4; nt++) o[nt][r] *= alpha;
        }

        // P (C/D layout) -> LDS hi/lo -> A-operand layout
        #pragma unroll
        for (int nt = 0; nt < 4; nt++)
            #pragma unroll
            for (int r = 0; r < 4; r++) {
                unsigned short hh, ll;
                split2(s[nt][r], hh, ll);
                pldh[wave][quad * 4 + r][nt * 16 + l16] = hh;
                pldl[wave][quad * 4 + r][nt * 16 + l16] = ll;
            }
        __syncthreads();

        // O += P V (split: Ph*Vh + Pl*Vh + Ph*Vl)
        #pragma unroll
        for (int kk = 0; kk < 2; kk++) {
            bf16x8 pah = *(const bf16x8*)&pldh[wave][l16][kk * 32 + quad * 8];
            bf16x8 pal = *(const bf16x8*)&pldl[wave][l16][kk * 32 + quad * 8];
            #pragma unroll
            for (int nt = 0; nt < 4; nt++) {
                bf16x8 vbh = *(const bf16x8*)&vth[nt * 16 + l16][kk * 32 + quad * 8];
                bf16x8 vbl = *(const bf16x8*)&vtl[nt * 16 + l16][kk * 32 + quad * 8];
                o[nt] = MFMA(pah, vbh, o[nt]);
                o[nt] = MFMA(pal, vbh, o[nt]);
                o[nt] = MFMA(pah, vbl, o[nt]);
            }
        }
        __syncthreads();   // protect vt/pld before next stage
    }

    // epilogue: /l_i, * qh (f32 from hi+lo), split-store to x2 planes
    #pragma unroll
    for (int r = 0; r < 4; r++) {
        int row = qbase + wave * 16 + quad * 4 + r;
        float inv = 1.0f / l_i[r];
        #pragma unroll
        for (int nt = 0; nt < 4; nt++) {
            int col = nt * 16 + l16;
            float qv = b2f(qph[(size_t)row * DK + col]) + b2f(qpl[(size_t)row * DK + col]);
            float val = o[nt][r] * inv * qv;
            unsigned short hh, ll;
            split2(val, hh, ll);
            size_t oo = ((size_t)b * L_ + row) * DM + h * DK + col;
            x2_hi[oo] = hh;
            x2_lo[oo] = ll;
        }
    }
}

// ---------------------------------------------------------------------------
// K3: output projection  out = X2 @ w_proj^T + b_proj  (split-precision, f32 out)
// ---------------------------------------------------------------------------
__global__ __launch_bounds__(256) void k3_out_proj(
    const unsigned short* __restrict__ x2_hi, const unsigned short* __restrict__ x2_lo,
    const unsigned short* __restrict__ wp_hi, const unsigned short* __restrict__ wp_lo,
    const float* __restrict__ bias,
    float* __restrict__ out)
{
    int bx = blockIdx.x;
    int mt  = bx >> 4;
    int ntb = bx & 15;
    int mbase = mt * 128, nbase = ntb * 64;

    int wave = threadIdx.x >> 6, lane = threadIdx.x & 63;
    int quad = lane >> 4, l16 = lane & 15;
    int row0 = mbase + wave * 32;

    f32x4 acc[2][4];
    #pragma unroll
    for (int i = 0; i < 2; i++)
        #pragma unroll
        for (int j = 0; j < 4; j++) acc[i][j] = (f32x4)0.0f;

    for (int c = 0; c < DM; c += 32) {
        int koff = c + quad * 8;
        size_t ao0 = (size_t)(row0 + l16) * DM + koff;
        size_t ao1 = (size_t)(row0 + 16 + l16) * DM + koff;
        bf16x8 a0h = ld8(x2_hi + ao0), a0l = ld8(x2_lo + ao0);
        bf16x8 a1h = ld8(x2_hi + ao1), a1l = ld8(x2_lo + ao1);
        #pragma unroll
        for (int nt = 0; nt < 4; nt++) {
            size_t bo = (size_t)(nbase + nt * 16 + l16) * DM + koff;
            bf16x8 bh = ld8(wp_hi + bo);
            bf16x8 bl = ld8(wp_lo + bo);
            acc[0][nt] = MFMA(a0h, bh, acc[0][nt]);
            acc[0][nt] = MFMA(a0l, bh, acc[0][nt]);
            acc[0][nt] = MFMA(a0h, bl, acc[0][nt]);
            acc[1][nt] = MFMA(a1h, bh, acc[1][nt]);
            acc[1][nt] = MFMA(a1l, bh, acc[1][nt]);
            acc[1][nt] = MFMA(a1h, bl, acc[1][nt]);
        }
    }

    #pragma unroll
    for (int mt2 = 0; mt2 < 2; mt2++)
        #pragma unroll
        for (int nt = 0; nt < 4; nt++)
            #pragma unroll
            for (int r = 0; r < 4; r++) {
                int row = row0 + mt2 * 16 + quad * 4 + r;
                int col = nbase + nt * 16 + l16;
                out[(size_t)row * DM + col] = acc[mt2][nt][r] + bias[col];
            }
}

// ---------------------------------------------------------------------------
extern "C" void kernel_launch(void* const* d_in, const int* in_sizes, int n_in,
                              void* d_out, int out_size, void* d_ws, size_t ws_size,
                              hipStream_t stream)
{
    const float* q     = (const float*)d_in[0];
    const float* k     = (const float*)d_in[1];
    const float* v     = (const float*)d_in[2];
    const float* wqs   = (const float*)d_in[3];
    const float* wks   = (const float*)d_in[4];
    const float* wvs   = (const float*)d_in[5];
    const float* wproj = (const float*)d_in[6];
    const float* bproj = (const float*)d_in[7];
    float* out = (float*)d_out;

    char* ws = (char*)d_ws;
    #define MB (size_t)(1024 * 1024)
    unsigned short* wt_hi = (unsigned short*)(ws);              // 6 MB
    unsigned short* wt_lo = (unsigned short*)(ws + 6  * MB);    // 6 MB
    unsigned short* wp_hi = (unsigned short*)(ws + 12 * MB);    // 2 MB
    unsigned short* wp_lo = (unsigned short*)(ws + 14 * MB);    // 2 MB
    unsigned short* qh_hi = (unsigned short*)(ws + 16 * MB);    // 8 MB
    unsigned short* qh_lo = (unsigned short*)(ws + 24 * MB);    // 8 MB
    unsigned short* kh_hi = (unsigned short*)(ws + 32 * MB);    // 8 MB
    unsigned short* kh_lo = (unsigned short*)(ws + 40 * MB);    // 8 MB
    unsigned short* vh_hi = (unsigned short*)(ws + 48 * MB);    // 8 MB
    unsigned short* vh_lo = (unsigned short*)(ws + 56 * MB);    // 8 MB
    unsigned short* x2_hi = (unsigned short*)(ws + 64 * MB);    // 8 MB
    unsigned short* x2_lo = (unsigned short*)(ws + 72 * MB);    // 8 MB  (total 80 MB)

    k0_transpose_w<<<dim3(3 * H_ * 16), dim3(256), 0, stream>>>(wqs, wks, wvs, wt_hi, wt_lo);
    k0b_cvt_wp<<<dim3((DM * DM) / (256 * 4)), dim3(256), 0, stream>>>(wproj, wp_hi, wp_lo);
    k1_proj_qkv<<<dim3(3 * H_ * 32), dim3(256), 0, stream>>>(q, k, v, wt_hi, wt_lo,
                                                             qh_hi, qh_lo, kh_hi, kh_lo, vh_hi, vh_lo);
    k2_attn<<<dim3(H_ * B_ * 32), dim3(256), 0, stream>>>(qh_hi, qh_lo, kh_hi, kh_lo,
                                                          vh_hi, vh_lo, x2_hi, x2_lo);
    k3_out_proj<<<dim3((ROWS / 128) * (DM / 64)), dim3(256), 0, stream>>>(x2_hi, x2_lo, wp_hi, wp_lo, bproj, out);
}

// Round 4
// 542.386 us; speedup vs baseline: 1.2998x; 1.2998x over previous
//
#include <hip/hip_runtime.h>

#define B_ 2
#define L_ 2048
#define DM 1024
#define H_ 16
#define DK 64
#define ROWS (B_*L_)   // 4096

typedef _Float16 f16x8 __attribute__((ext_vector_type(8)));
typedef float    f32x4 __attribute__((ext_vector_type(4)));
typedef unsigned short us8 __attribute__((ext_vector_type(8)));

__device__ __forceinline__ unsigned short f2h(float f) {
    _Float16 h = (_Float16)f;
    return __builtin_bit_cast(unsigned short, h);
}
__device__ __forceinline__ float h2f(unsigned short u) {
    return (float)__builtin_bit_cast(_Float16, u);
}
__device__ __forceinline__ f16x8 ld8h(const unsigned short* p) {
    return *reinterpret_cast<const f16x8*>(p);
}

#define MFMA(a, b, c) __builtin_amdgcn_mfma_f32_16x16x32_f16((a), (b), (c), 0, 0, 0)

// ---------------------------------------------------------------------------
// kcvt: f32 -> fp16 bulk convert (8 elems/thread)
// ---------------------------------------------------------------------------
__global__ __launch_bounds__(256) void kcvt(
    const float* __restrict__ src, unsigned short* __restrict__ dst)
{
    size_t i = ((size_t)blockIdx.x * 256 + threadIdx.x) * 8;
    const float4* s4 = (const float4*)(src + i);
    float4 a = s4[0], b = s4[1];
    us8 u;
    u[0] = f2h(a.x); u[1] = f2h(a.y); u[2] = f2h(a.z); u[3] = f2h(a.w);
    u[4] = f2h(b.x); u[5] = f2h(b.y); u[6] = f2h(b.z); u[7] = f2h(b.w);
    *(us8*)(dst + i) = u;
}

// ---------------------------------------------------------------------------
// K0: transpose per-head weights (f32) [3][H][DM][DK] -> fp16 [3][H][DK][DM]
// ---------------------------------------------------------------------------
__global__ __launch_bounds__(256) void k0_transpose_w(
    const float* __restrict__ wq,
    const float* __restrict__ wk,
    const float* __restrict__ wv,
    unsigned short* __restrict__ wt)
{
    __shared__ unsigned short tile[64][65];
    int bx = blockIdx.x;
    int which = bx / (H_ * 16);
    int rem   = bx % (H_ * 16);
    int h  = rem >> 4;
    int db = (rem & 15) * 64;
    const float* src = (which == 0) ? wq : (which == 1) ? wk : wv;

    int t = threadIdx.x;
    int r = t >> 2;             // d offset 0..63
    int c = (t & 3) * 16;       // dk offset {0,16,32,48}
    const float4* sp = (const float4*)(src + ((size_t)(h * DM + db + r)) * DK + c);
    #pragma unroll
    for (int i4 = 0; i4 < 4; i4++) {
        float4 f = sp[i4];
        tile[r][c + i4 * 4 + 0] = f2h(f.x);
        tile[r][c + i4 * 4 + 1] = f2h(f.y);
        tile[r][c + i4 * 4 + 2] = f2h(f.z);
        tile[r][c + i4 * 4 + 3] = f2h(f.w);
    }
    __syncthreads();

    int n   = t >> 2;           // dk index 0..63
    int d16 = (t & 3) * 16;
    __align__(16) unsigned short ov[16];
    #pragma unroll
    for (int i = 0; i < 16; i++) ov[i] = tile[d16 + i][n];
    size_t off = (((size_t)which * H_ + h) * DK + n) * DM + db + d16;
    *(us8*)(wt + off)     = *(us8*)&ov[0];
    *(us8*)(wt + off + 8) = *(us8*)&ov[8];
}

// ---------------------------------------------------------------------------
// K1: fused q/k/v per-head projection GEMM, fp16 single-term.
// Block: (which, 128-row M tile, head). 4 waves x 32 rows x 64 cols.
// which==2 (V): output transposed via LDS -> vt [H][DK][ROWS].
// ---------------------------------------------------------------------------
__global__ __launch_bounds__(256) void k1_proj_qkv(
    const unsigned short* __restrict__ xh,   // fp16 [3][ROWS][DM]
    const unsigned short* __restrict__ wt,   // fp16 [3][H][DK][DM]
    unsigned short* __restrict__ qh,         // fp16 [H][ROWS][DK]
    unsigned short* __restrict__ kh,         // fp16 [H][ROWS][DK]
    unsigned short* __restrict__ vt)         // fp16 [H][DK][ROWS]
{
    __shared__ unsigned short vtile[64][137];   // [dk][row_rel] for V transpose

    int bx = blockIdx.x;
    int which = bx / (H_ * 32);
    int rem   = bx % (H_ * 32);
    int h     = rem & 15;          // h fastest: consecutive blocks share A tile
    int mbase = (rem >> 4) * 128;

    const unsigned short* X = xh + (size_t)which * ROWS * DM;
    const unsigned short* W = wt + ((size_t)which * H_ + h) * DK * DM;

    int wave = threadIdx.x >> 6, lane = threadIdx.x & 63;
    int quad = lane >> 4, l16 = lane & 15;
    int row0 = mbase + wave * 32;

    f32x4 acc[2][4];
    #pragma unroll
    for (int i = 0; i < 2; i++)
        #pragma unroll
        for (int j = 0; j < 4; j++) acc[i][j] = (f32x4)0.0f;

    for (int d = 0; d < DM; d += 32) {
        int koff = d + quad * 8;
        f16x8 a0 = ld8h(X + (size_t)(row0 + l16) * DM + koff);
        f16x8 a1 = ld8h(X + (size_t)(row0 + 16 + l16) * DM + koff);
        #pragma unroll
        for (int nt = 0; nt < 4; nt++) {
            f16x8 bfr = ld8h(W + (size_t)(nt * 16 + l16) * DM + koff);
            acc[0][nt] = MFMA(a0, bfr, acc[0][nt]);
            acc[1][nt] = MFMA(a1, bfr, acc[1][nt]);
        }
    }

    if (which < 2) {
        unsigned short* OUT = ((which == 0) ? qh : kh) + (size_t)h * ROWS * DK;
        #pragma unroll
        for (int mt = 0; mt < 2; mt++)
            #pragma unroll
            for (int nt = 0; nt < 4; nt++)
                #pragma unroll
                for (int r = 0; r < 4; r++) {
                    int row = row0 + mt * 16 + quad * 4 + r;
                    OUT[(size_t)row * DK + nt * 16 + l16] = f2h(acc[mt][nt][r]);
                }
    } else {
        // transpose 128x64 tile through LDS, write vt[h][dk][row] coalesced
        #pragma unroll
        for (int mt = 0; mt < 2; mt++)
            #pragma unroll
            for (int nt = 0; nt < 4; nt++)
                #pragma unroll
                for (int r = 0; r < 4; r++) {
                    int rrel = wave * 32 + mt * 16 + quad * 4 + r;
                    vtile[nt * 16 + l16][rrel] = f2h(acc[mt][nt][r]);
                }
        __syncthreads();
        int t  = threadIdx.x;
        int dk = t >> 2;
        int sg = (t & 3) * 32;
        __align__(16) unsigned short ov[32];
        #pragma unroll
        for (int i = 0; i < 32; i++) ov[i] = vtile[dk][sg + i];
        unsigned short* dp = vt + ((size_t)h * DK + dk) * ROWS + mbase + sg;
        #pragma unroll
        for (int i8 = 0; i8 < 4; i8++)
            *(us8*)(dp + i8 * 8) = *(us8*)&ov[i8 * 8];
    }
}

// ---------------------------------------------------------------------------
// K2: flash attention per (h, b, 64-row Q tile), fp16, barrier-free K-loop.
// K fragments direct from global; V^T fragments direct from global (vt);
// P round-trips through a PER-WAVE LDS slice (no __syncthreads needed).
// ---------------------------------------------------------------------------
__global__ __launch_bounds__(256) void k2_attn(
    const unsigned short* __restrict__ qh,   // fp16 [H][ROWS][DK]
    const unsigned short* __restrict__ kh,   // fp16 [H][ROWS][DK]
    const unsigned short* __restrict__ vt,   // fp16 [H][DK][ROWS]
    unsigned short* __restrict__ x2)         // fp16 [ROWS][DM]
{
    __shared__ __align__(16) unsigned short pld[4][16][72];   // per-wave P tile

    int bx = blockIdx.x;
    int h  = bx >> 6;
    int b  = (bx >> 5) & 1;
    int qt = bx & 31;
    int qbase = qt * 64;

    const unsigned short* qhp = qh + ((size_t)h * ROWS + b * L_) * DK;
    const unsigned short* khp = kh + ((size_t)h * ROWS + b * L_) * DK;
    const unsigned short* vtp = vt + (size_t)h * DK * ROWS + b * L_;

    int wave = threadIdx.x >> 6, lane = threadIdx.x & 63;
    int quad = lane >> 4, l16 = lane & 15;

    int qrow = qbase + wave * 16 + l16;
    f16x8 qa0 = ld8h(qhp + (size_t)qrow * DK + quad * 8);
    f16x8 qa1 = ld8h(qhp + (size_t)qrow * DK + 32 + quad * 8);

    float m_i[4], l_i[4];
    f32x4 o[4];
    #pragma unroll
    for (int r = 0; r < 4; r++) { m_i[r] = -1e30f; l_i[r] = 0.0f; }
    #pragma unroll
    for (int nt = 0; nt < 4; nt++) o[nt] = (f32x4)0.0f;

    for (int kt = 0; kt < 32; kt++) {
        int kb = kt * 64;

        // S = Q K^T  (wave: 16 q-rows x 64 keys)
        f32x4 s[4];
        #pragma unroll
        for (int nt = 0; nt < 4; nt++) s[nt] = (f32x4)0.0f;
        #pragma unroll
        for (int nt = 0; nt < 4; nt++) {
            const unsigned short* kp = khp + (size_t)(kb + nt * 16 + l16) * DK;
            f16x8 b0 = ld8h(kp + quad * 8);
            f16x8 b1 = ld8h(kp + 32 + quad * 8);
            s[nt] = MFMA(qa0, b0, s[nt]);
            s[nt] = MFMA(qa1, b1, s[nt]);
        }

        // online softmax (rows owned by this quad: quad*4 + r)
        #pragma unroll
        for (int r = 0; r < 4; r++) {
            float mx = fmaxf(fmaxf(s[0][r], s[1][r]), fmaxf(s[2][r], s[3][r]));
            #pragma unroll
            for (int off = 1; off < 16; off <<= 1)
                mx = fmaxf(mx, __shfl_xor(mx, off, 16));
            float mnew  = fmaxf(m_i[r], mx);
            float alpha = __expf(m_i[r] - mnew);
            float rs = 0.0f;
            #pragma unroll
            for (int nt = 0; nt < 4; nt++) {
                float p = __expf(s[nt][r] - mnew);
                s[nt][r] = p;
                rs += p;
            }
            #pragma unroll
            for (int off = 1; off < 16; off <<= 1)
                rs += __shfl_xor(rs, off, 16);
            l_i[r] = l_i[r] * alpha + rs;
            m_i[r] = mnew;
            #pragma unroll
            for (int nt = 0; nt < 4; nt++) o[nt][r] *= alpha;
        }

        // P (C/D layout) -> per-wave LDS -> A-operand layout (no barrier!)
        #pragma unroll
        for (int nt = 0; nt < 4; nt++)
            #pragma unroll
            for (int r = 0; r < 4; r++)
                pld[wave][quad * 4 + r][nt * 16 + l16] = f2h(s[nt][r]);

        // O += P V  (V^T fragments straight from global, key-contiguous)
        #pragma unroll
        for (int kk = 0; kk < 2; kk++) {
            f16x8 pa = *(const f16x8*)&pld[wave][l16][kk * 32 + quad * 8];
            #pragma unroll
            for (int nt = 0; nt < 4; nt++) {
                f16x8 vb = ld8h(vtp + (size_t)(nt * 16 + l16) * ROWS + kb + kk * 32 + quad * 8);
                o[nt] = MFMA(pa, vb, o[nt]);
            }
        }
    }

    // epilogue: /l_i, * qh, head-concat store (fp16)
    #pragma unroll
    for (int r = 0; r < 4; r++) {
        int row = qbase + wave * 16 + quad * 4 + r;
        float inv = 1.0f / l_i[r];
        #pragma unroll
        for (int nt = 0; nt < 4; nt++) {
            int col = nt * 16 + l16;
            float qv = h2f(qhp[(size_t)row * DK + col]);
            float val = o[nt][r] * inv * qv;
            x2[((size_t)b * L_ + row) * DM + h * DK + col] = f2h(val);
        }
    }
}

// ---------------------------------------------------------------------------
// K3: output projection  out = X2 @ w_proj^T + b_proj  (fp16 inputs, f32 out)
// ---------------------------------------------------------------------------
__global__ __launch_bounds__(256) void k3_out_proj(
    const unsigned short* __restrict__ x2,     // fp16 [ROWS][DM]
    const unsigned short* __restrict__ wph,    // fp16 [DM][DM] (row = out dim)
    const float* __restrict__ bias,
    float* __restrict__ out)
{
    int bx = blockIdx.x;
    int mt  = bx >> 4;
    int ntb = bx & 15;
    int mbase = mt * 128, nbase = ntb * 64;

    int wave = threadIdx.x >> 6, lane = threadIdx.x & 63;
    int quad = lane >> 4, l16 = lane & 15;
    int row0 = mbase + wave * 32;

    f32x4 acc[2][4];
    #pragma unroll
    for (int i = 0; i < 2; i++)
        #pragma unroll
        for (int j = 0; j < 4; j++) acc[i][j] = (f32x4)0.0f;

    for (int c = 0; c < DM; c += 32) {
        int koff = c + quad * 8;
        f16x8 a0 = ld8h(x2 + (size_t)(row0 + l16) * DM + koff);
        f16x8 a1 = ld8h(x2 + (size_t)(row0 + 16 + l16) * DM + koff);
        #pragma unroll
        for (int nt = 0; nt < 4; nt++) {
            f16x8 bfr = ld8h(wph + (size_t)(nbase + nt * 16 + l16) * DM + koff);
            acc[0][nt] = MFMA(a0, bfr, acc[0][nt]);
            acc[1][nt] = MFMA(a1, bfr, acc[1][nt]);
        }
    }

    #pragma unroll
    for (int mt2 = 0; mt2 < 2; mt2++)
        #pragma unroll
        for (int nt = 0; nt < 4; nt++)
            #pragma unroll
            for (int r = 0; r < 4; r++) {
                int row = row0 + mt2 * 16 + quad * 4 + r;
                int col = nbase + nt * 16 + l16;
                out[(size_t)row * DM + col] = acc[mt2][nt][r] + bias[col];
            }
}

// ---------------------------------------------------------------------------
extern "C" void kernel_launch(void* const* d_in, const int* in_sizes, int n_in,
                              void* d_out, int out_size, void* d_ws, size_t ws_size,
                              hipStream_t stream)
{
    const float* q     = (const float*)d_in[0];
    const float* k     = (const float*)d_in[1];
    const float* v     = (const float*)d_in[2];
    const float* wqs   = (const float*)d_in[3];
    const float* wks   = (const float*)d_in[4];
    const float* wvs   = (const float*)d_in[5];
    const float* wproj = (const float*)d_in[6];
    const float* bproj = (const float*)d_in[7];
    float* out = (float*)d_out;

    char* ws = (char*)d_ws;
    #define MB (size_t)(1024 * 1024)
    unsigned short* xh  = (unsigned short*)(ws);            // 24 MB (3 x 8 MB)
    unsigned short* wt  = (unsigned short*)(ws + 24 * MB);  // 6 MB
    unsigned short* wph = (unsigned short*)(ws + 30 * MB);  // 2 MB
    unsigned short* qh  = (unsigned short*)(ws + 32 * MB);  // 8 MB
    unsigned short* kh  = (unsigned short*)(ws + 40 * MB);  // 8 MB
    unsigned short* vt  = (unsigned short*)(ws + 48 * MB);  // 8 MB
    unsigned short* x2  = (unsigned short*)(ws + 56 * MB);  // 8 MB (total 64 MB)

    // f32 -> fp16 conversions
    kcvt<<<dim3((ROWS * DM) / (256 * 8)), dim3(256), 0, stream>>>(q, xh);
    kcvt<<<dim3((ROWS * DM) / (256 * 8)), dim3(256), 0, stream>>>(k, xh + (size_t)ROWS * DM);
    kcvt<<<dim3((ROWS * DM) / (256 * 8)), dim3(256), 0, stream>>>(v, xh + (size_t)2 * ROWS * DM);
    kcvt<<<dim3((DM * DM) / (256 * 8)), dim3(256), 0, stream>>>(wproj, wph);
    k0_transpose_w<<<dim3(3 * H_ * 16), dim3(256), 0, stream>>>(wqs, wks, wvs, wt);

    k1_proj_qkv<<<dim3(3 * H_ * 32), dim3(256), 0, stream>>>(xh, wt, qh, kh, vt);
    k2_attn<<<dim3(H_ * B_ * 32), dim3(256), 0, stream>>>(qh, kh, vt, x2);
    k3_out_proj<<<dim3((ROWS / 128) * (DM / 64)), dim3(256), 0, stream>>>(x2, wph, bproj, out);
}